// Round 1
// baseline (816.401 us; speedup 1.0000x reference)
//
#include <hip/hip_runtime.h>
#include <math.h>

// Problem constants
#define NSUB   3
#define CFEAT  1024
#define KDIM   3072          // 3 * 32 * 32
#define MDIM   1568          // 32 * 49
#define BATCH  32

// GEMM tiling
#define BM 128
#define BN 64
#define BK 32
#define LDSP 36              // padded leading dim (floats): 16B-aligned, conflict-free reads

// Output layout (flat f32), in reference return order:
//   ranking [32,3]                         offset 0      size 96
//   cam     3 branches x 2 maps [32,7,7]   offset 96     size 6*1568 = 9408
//   feats   3 x [32,1024,7,7]              offset 9504   size 3*1605632
#define OUT_CAM   96
#define OUT_FEAT  9504
#define FEAT_PER_BRANCH (BATCH * CFEAT * 49)   // 1605632

// ---------------------------------------------------------------------------
// Conv-as-GEMM: feats[i][b][c][p] = sum_k x_patch[m=(b,p)][k] * W[i][c][k] + bb[i][c]
// k = ch*1024 + r*32 + s ; patch addr = ((b*3+ch)*224 + ph*32+r)*224 + pw*32+s
// ---------------------------------------------------------------------------
__global__ __launch_bounds__(256) void conv_gemm(
    const float* __restrict__ x, const float* __restrict__ Wb,
    const float* __restrict__ bb, float* __restrict__ out)
{
    __shared__ float As[BM][LDSP];
    __shared__ float Bs[BN][LDSP];

    const int bid = blockIdx.x;
    const int i   = bid / 208;          // branch
    const int rem = bid % 208;
    const int mt  = rem / 16;           // 13 m-tiles (13*128 = 1664 >= 1568)
    const int nt  = rem % 16;           // 16 n-tiles of 64

    const int t     = threadIdx.x;
    const int row_l = t >> 3;           // 0..31
    const int c4    = t & 7;            // 0..7  (float4 column within BK)

    // Hoist A-source bases (independent of k-tile)
    int  abase[4];
    bool avalid[4];
#pragma unroll
    for (int l = 0; l < 4; ++l) {
        int m = mt * BM + row_l + l * 32;
        avalid[l] = (m < MDIM);
        if (avalid[l]) {
            int b = m / 49, p = m % 49;
            int ph = p / 7, pw = p % 7;
            abase[l] = ((b * 3) * 224 + ph * 32) * 224 + pw * 32;
        } else abase[l] = 0;
    }
    const float* wbr = Wb + (size_t)i * CFEAT * KDIM;
    const int nrow0 = nt * BN + row_l;  // B rows this thread stages (l=0..1)

    float acc[8][4];
#pragma unroll
    for (int r = 0; r < 8; ++r)
#pragma unroll
        for (int c = 0; c < 4; ++c) acc[r][c] = 0.f;

    const int tx = t & 15;              // n micro index
    const int ty = t >> 4;              // m micro index

    for (int kt = 0; kt < KDIM / BK; ++kt) {
        const int ch = kt >> 5, r = kt & 31;
        const int aoff = ch * 50176 + r * 224 + c4 * 4;

        float4 av[4];
#pragma unroll
        for (int l = 0; l < 4; ++l)
            av[l] = avalid[l] ? *(const float4*)(x + abase[l] + aoff)
                              : make_float4(0.f, 0.f, 0.f, 0.f);
        float4 bv[2];
#pragma unroll
        for (int l = 0; l < 2; ++l)
            bv[l] = *(const float4*)(wbr + (size_t)(nrow0 + l * 32) * KDIM + kt * BK + c4 * 4);

        __syncthreads();
#pragma unroll
        for (int l = 0; l < 4; ++l)
            *(float4*)&As[row_l + l * 32][c4 * 4] = av[l];
        if (row_l < 32) {  // always true; keep symmetric stores simple
#pragma unroll
            for (int l = 0; l < 2; ++l)
                *(float4*)&Bs[row_l + l * 32][c4 * 4] = bv[l];
        }
        __syncthreads();

#pragma unroll
        for (int k = 0; k < BK; ++k) {
            float a[8], b[4];
#pragma unroll
            for (int r8 = 0; r8 < 8; ++r8) a[r8] = As[ty + 16 * r8][k];
#pragma unroll
            for (int c8 = 0; c8 < 4; ++c8) b[c8] = Bs[tx + 16 * c8][k];
#pragma unroll
            for (int r8 = 0; r8 < 8; ++r8)
#pragma unroll
                for (int c8 = 0; c8 < 4; ++c8)
                    acc[r8][c8] += a[r8] * b[c8];
        }
    }

    // Epilogue: add bias, scatter into feats[i][b][c][p]
    float* feat = out + OUT_FEAT + (size_t)i * FEAT_PER_BRANCH;
    float bias[4];
#pragma unroll
    for (int c8 = 0; c8 < 4; ++c8)
        bias[c8] = bb[i * CFEAT + nt * BN + tx + 16 * c8];
#pragma unroll
    for (int r8 = 0; r8 < 8; ++r8) {
        int m = mt * BM + ty + 16 * r8;
        if (m >= MDIM) continue;
        int b = m / 49, p = m % 49;
#pragma unroll
        for (int c8 = 0; c8 < 4; ++c8) {
            int n = nt * BN + tx + 16 * c8;
            feat[(size_t)(b * CFEAT + n) * 49 + p] = acc[r8][c8] + bias[c8];
        }
    }
}

// ---------------------------------------------------------------------------
// Global average pool: pooled[i][b][c] = mean_p feats[i][b][c][p]
// feats chunks are contiguous across branches -> flat index * 49
// ---------------------------------------------------------------------------
__global__ void pool_kernel(const float* __restrict__ feat, float* __restrict__ pooled)
{
    int idx = blockIdx.x * blockDim.x + threadIdx.x;   // 0 .. 3*32*1024-1
    const float* f = feat + (size_t)idx * 49;
    float s = 0.f;
#pragma unroll
    for (int p = 0; p < 49; ++p) s += f[p];
    pooled[idx] = s * (1.f / 49.f);
}

// ---------------------------------------------------------------------------
// CAM: cam[i][o][b][p] = relu(sum_c cls_w[i][o][c] * feats[i][b][c][p])
// ---------------------------------------------------------------------------
__global__ void cam_kernel(const float* __restrict__ feat,
                           const float* __restrict__ cls_w,
                           float* __restrict__ out_cam)
{
    int i = blockIdx.x / BATCH;
    int b = blockIdx.x % BATCH;
    int t = threadIdx.x;
    if (t >= 98) return;
    int o = t / 49, p = t % 49;
    const float* f = feat + ((size_t)i * BATCH + b) * CFEAT * 49 + p;
    const float* w = cls_w + ((size_t)i * 2 + o) * CFEAT;
    float s = 0.f;
    for (int c = 0; c < CFEAT; ++c) s += w[c] * f[(size_t)c * 49];
    out_cam[((size_t)i * 2 + o) * MDIM + b * 49 + p] = fmaxf(s, 0.f);
}

// ---------------------------------------------------------------------------
// MLP layer 1: h[i][b][j] = relu(pooled[i][b][:] . p1_w[i][j][:] + p1_b[i][j])
// ---------------------------------------------------------------------------
__global__ void mlp1_kernel(const float* __restrict__ pooled,
                            const float* __restrict__ p1_w,
                            const float* __restrict__ p1_b,
                            float* __restrict__ h)
{
    int i  = blockIdx.x / 16;
    int jc = blockIdx.x % 16;
    int t  = threadIdx.x;
    int j  = jc * 32 + (t & 31);
    int b0 = t >> 5;                    // 0..7
    const float* wrow = p1_w + ((size_t)i * 512 + j) * CFEAT;
    float bias = p1_b[i * 512 + j];
    for (int bo = 0; bo < BATCH; bo += 8) {
        int b = b0 + bo;
        const float* pv = pooled + ((size_t)i * BATCH + b) * CFEAT;
        float s = bias;
        for (int k = 0; k < CFEAT; k += 4) {
            float4 w4 = *(const float4*)(wrow + k);
            float4 v4 = *(const float4*)(pv + k);
            s += w4.x * v4.x + w4.y * v4.y + w4.z * v4.z + w4.w * v4.w;
        }
        h[((size_t)i * BATCH + b) * 512 + j] = fmaxf(s, 0.f);
    }
}

// ---------------------------------------------------------------------------
// MLP layer 2 + softmax[:,1]: ranking[b][i] = sigmoid(l1 - l0)
// ---------------------------------------------------------------------------
__global__ void mlp2_kernel(const float* __restrict__ h,
                            const float* __restrict__ p2_w,
                            const float* __restrict__ p2_b,
                            float* __restrict__ out)
{
    int i = blockIdx.x;
    int b = threadIdx.x;
    if (b >= BATCH) return;
    const float* hv = h + ((size_t)i * BATCH + b) * 512;
    const float* w0 = p2_w + (size_t)i * 2 * 512;
    const float* w1 = w0 + 512;
    float l0 = p2_b[i * 2 + 0], l1 = p2_b[i * 2 + 1];
    for (int k = 0; k < 512; ++k) {
        float hk = hv[k];
        l0 += hk * w0[k];
        l1 += hk * w1[k];
    }
    out[b * NSUB + i] = 1.f / (1.f + expf(l0 - l1));
}

// ---------------------------------------------------------------------------
extern "C" void kernel_launch(void* const* d_in, const int* in_sizes, int n_in,
                              void* d_out, int out_size, void* d_ws, size_t ws_size,
                              hipStream_t stream)
{
    const float* x    = (const float*)d_in[0];
    const float* Wb   = (const float*)d_in[1];
    const float* bbp  = (const float*)d_in[2];
    const float* p1w  = (const float*)d_in[3];
    const float* p1b  = (const float*)d_in[4];
    const float* p2w  = (const float*)d_in[5];
    const float* p2b  = (const float*)d_in[6];
    const float* clsw = (const float*)d_in[7];
    float* out = (float*)d_out;

    // ws: pooled [3*32*1024] f32, then h [3*32*512] f32  (~590 KB)
    float* pooled = (float*)d_ws;
    float* hbuf   = pooled + NSUB * BATCH * CFEAT;

    // conv: 3 branches x 13 m-tiles x 16 n-tiles
    conv_gemm<<<NSUB * 13 * 16, 256, 0, stream>>>(x, Wb, bbp, out);
    pool_kernel<<<(NSUB * BATCH * CFEAT) / 256, 256, 0, stream>>>(out + OUT_FEAT, pooled);
    cam_kernel<<<NSUB * BATCH, 128, 0, stream>>>(out + OUT_FEAT, clsw, out + OUT_CAM);
    mlp1_kernel<<<NSUB * 16, 256, 0, stream>>>(pooled, p1w, p1b, hbuf);
    mlp2_kernel<<<NSUB, 64, 0, stream>>>(hbuf, p2w, p2b, out);
}

// Round 2
// 222.434 us; speedup vs baseline: 3.6703x; 3.6703x over previous
//
#include <hip/hip_runtime.h>
#include <hip/hip_bf16.h>
#include <math.h>

// Problem constants
#define NSUB   3
#define CFEAT  1024
#define KDIM   3072          // 3 * 32 * 32
#define MDIM   1568          // 32 * 49
#define BATCH  32

// Output layout (flat f32): ranking[32,3] | cam 3x2x[32,7,7] | feats 3x[32,1024,7,7]
#define OUT_CAM   96
#define OUT_FEAT  9504
#define FEAT_PER_BRANCH (BATCH * CFEAT * 49)   // 1605632

typedef __attribute__((ext_vector_type(8))) short bf16x8;
typedef __attribute__((ext_vector_type(4))) float f32x4;

__device__ __forceinline__ short b16(float f){
    __hip_bfloat16 h = __float2bfloat16(f);
    return *reinterpret_cast<short*>(&h);
}
__device__ __forceinline__ bf16x8 pack8(float4 a, float4 b){
    bf16x8 r;
    r[0]=b16(a.x); r[1]=b16(a.y); r[2]=b16(a.z); r[3]=b16(a.w);
    r[4]=b16(b.x); r[5]=b16(b.y); r[6]=b16(b.z); r[7]=b16(b.w);
    return r;
}

// ---------------------------------------------------------------------------
// Conv-as-GEMM, bf16 MFMA. C[m=(b,p)][n=c] = sum_k A[m][k] * W[n][k] + bias
// Tile: BM=128, BN=64, BK=64. 4 waves (2x2), each wave 64x32 (4x2 frags 16x16).
// LDS: A [128 rows][64 bf16] (128B rows) + B [64][64]; XOR swizzle slot^=(row&7)
// -> conflict-free ds_read_b128 (T2). Grid 3*13*16 = 624, XCD-chunked swizzle.
// ---------------------------------------------------------------------------
__global__ __launch_bounds__(256) void conv_mfma(
    const float* __restrict__ x, const float* __restrict__ Wb,
    const float* __restrict__ bb, float* __restrict__ out)
{
    __shared__ __align__(16) char lds[24576];   // A: 16KB @0, B: 8KB @16384

    int bid = (int)blockIdx.x;
    bid = (bid & 7) * 78 + (bid >> 3);          // bijective XCD swizzle (624 = 8*78)
    const int i   = bid / 208;
    const int rem = bid % 208;
    const int mt  = rem >> 4, nt = rem & 15;

    const int t = threadIdx.x;

    // ---- staging geometry: thread stages A slots rows {srow+32q, q=0..3},
    //      B rows {srow+32q, q=0..1}, slot ssl (8 bf16 = 16B each) ----
    const int srow = t >> 3;                    // 0..31
    const int ssl  = t & 7;                     // 0..7
    const int wsl  = ssl ^ (srow & 7);          // swizzled 16B slot
    const int sk   = (ssl & 3) * 8;             // k%32 start
    const int skh  = ssl >> 2;                  // +1 image row if ssl>=4

    int  abase[4]; bool aval[4];
#pragma unroll
    for (int q = 0; q < 4; ++q) {
        int m = mt*128 + q*32 + srow;
        aval[q] = (m < MDIM);
        if (aval[q]) { int b = m/49, p = m%49, ph = p/7, pw = p%7;
                       abase[q] = ((b*3)*224 + ph*32)*224 + pw*32; }
        else abase[q] = 0;
    }
    const float* wb = Wb + (size_t)i * CFEAT * KDIM;
    const float* bsrc[2];
#pragma unroll
    for (int q = 0; q < 2; ++q)
        bsrc[q] = wb + (size_t)(nt*64 + q*32 + srow) * KDIM + ssl*8;

    int awr[4], bwr[2];
#pragma unroll
    for (int q = 0; q < 4; ++q) awr[q] = (q*32 + srow)*128 + wsl*16;
#pragma unroll
    for (int q = 0; q < 2; ++q) bwr[q] = 16384 + (q*32 + srow)*128 + wsl*16;

    // ---- compute geometry ----
    const int wv = t >> 6, l = t & 63;
    const int wr = wv >> 1, wc = wv & 1;        // wave grid 2x2
    const int lrow = l & 15, lsl = l >> 4;
    int ard[4][2], brd[2][2];
#pragma unroll
    for (int mi = 0; mi < 4; ++mi) {
        int row = wr*64 + mi*16 + lrow;
        ard[mi][0] = row*128 + ((lsl    ) ^ (row & 7))*16;
        ard[mi][1] = row*128 + ((lsl + 4) ^ (row & 7))*16;
    }
#pragma unroll
    for (int ni = 0; ni < 2; ++ni) {
        int row = wc*32 + ni*16 + lrow;
        brd[ni][0] = 16384 + row*128 + ((lsl    ) ^ (row & 7))*16;
        brd[ni][1] = 16384 + row*128 + ((lsl + 4) ^ (row & 7))*16;
    }

    f32x4 acc[4][2];
#pragma unroll
    for (int mi = 0; mi < 4; ++mi)
#pragma unroll
        for (int ni = 0; ni < 2; ++ni) acc[mi][ni] = (f32x4){0.f,0.f,0.f,0.f};

    for (int kt = 0; kt < KDIM/64; ++kt) {
        // global loads (f32) + convert
        const int kr   = kt*2 + skh;
        const int koff = (kr >> 5)*50176 + (kr & 31)*224 + sk;
        float4 av[4][2], bv[2][2];
#pragma unroll
        for (int q = 0; q < 4; ++q) {
            const float* p = x + abase[q] + koff;
            av[q][0] = aval[q] ? *(const float4*)p       : make_float4(0,0,0,0);
            av[q][1] = aval[q] ? *(const float4*)(p + 4) : make_float4(0,0,0,0);
        }
#pragma unroll
        for (int q = 0; q < 2; ++q) {
            const float* p = bsrc[q] + kt*64;
            bv[q][0] = *(const float4*)p;
            bv[q][1] = *(const float4*)(p + 4);
        }
        __syncthreads();
#pragma unroll
        for (int q = 0; q < 4; ++q) *(bf16x8*)(lds + awr[q]) = pack8(av[q][0], av[q][1]);
#pragma unroll
        for (int q = 0; q < 2; ++q) *(bf16x8*)(lds + bwr[q]) = pack8(bv[q][0], bv[q][1]);
        __syncthreads();

        bf16x8 af[4][2], bf[2][2];
#pragma unroll
        for (int mi = 0; mi < 4; ++mi)
#pragma unroll
            for (int kk = 0; kk < 2; ++kk)
                af[mi][kk] = *(const bf16x8*)(lds + ard[mi][kk]);
#pragma unroll
        for (int ni = 0; ni < 2; ++ni)
#pragma unroll
            for (int kk = 0; kk < 2; ++kk)
                bf[ni][kk] = *(const bf16x8*)(lds + brd[ni][kk]);
#pragma unroll
        for (int kk = 0; kk < 2; ++kk)
#pragma unroll
            for (int mi = 0; mi < 4; ++mi)
#pragma unroll
                for (int ni = 0; ni < 2; ++ni)
                    acc[mi][ni] = __builtin_amdgcn_mfma_f32_16x16x32_bf16(
                        af[mi][kk], bf[ni][kk], acc[mi][ni], 0, 0, 0);
    }

    // epilogue: bias + scatter to feats[i][b][c][p]
    float* featb = out + OUT_FEAT + (size_t)i * FEAT_PER_BRANCH;
    float bias[2];
#pragma unroll
    for (int ni = 0; ni < 2; ++ni)
        bias[ni] = bb[i*CFEAT + nt*64 + wc*32 + ni*16 + lrow];
#pragma unroll
    for (int mi = 0; mi < 4; ++mi) {
        int mbase = mt*128 + wr*64 + mi*16 + lsl*4;
#pragma unroll
        for (int r = 0; r < 4; ++r) {
            int m = mbase + r;
            if (m >= MDIM) continue;
            int b = m/49, p = m%49;
#pragma unroll
            for (int ni = 0; ni < 2; ++ni) {
                int n = nt*64 + wc*32 + ni*16 + lrow;
                featb[(size_t)(b*CFEAT + n)*49 + p] = acc[mi][ni][r] + bias[ni];
            }
        }
    }
}

// ---------------------------------------------------------------------------
// Global average pool
// ---------------------------------------------------------------------------
__global__ void pool_kernel(const float* __restrict__ feat, float* __restrict__ pooled)
{
    int idx = blockIdx.x * blockDim.x + threadIdx.x;   // 0 .. 3*32*1024-1
    const float* f = feat + (size_t)idx * 49;
    float s = 0.f;
#pragma unroll
    for (int p = 0; p < 49; ++p) s += f[p];
    pooled[idx] = s * (1.f / 49.f);
}

// ---------------------------------------------------------------------------
// CAM: block per (i,b); 4 waves split channels; weights staged in LDS.
// ---------------------------------------------------------------------------
__global__ __launch_bounds__(256) void cam_kernel(
    const float* __restrict__ feat, const float* __restrict__ cls_w,
    float* __restrict__ out_cam)
{
    __shared__ float wsh[2048];
    __shared__ float part[2][4][49];
    int i = blockIdx.x >> 5, b = blockIdx.x & 31;
    int t = threadIdx.x;
    const float* w = cls_w + (size_t)i * 2 * CFEAT;
    for (int k = t; k < 2048; k += 256) wsh[k] = w[k];
    __syncthreads();
    int wv = t >> 6, l = t & 63;
    const float* f = feat + ((size_t)(i*BATCH + b)) * CFEAT * 49;
    if (l < 49) {
        float a0 = 0.f, a1 = 0.f;
        for (int c = wv*256; c < wv*256 + 256; ++c) {
            float v = f[(size_t)c*49 + l];
            a0 += wsh[c] * v;
            a1 += wsh[1024 + c] * v;
        }
        part[0][wv][l] = a0;
        part[1][wv][l] = a1;
    }
    __syncthreads();
    if (t < 98) {
        int o = t / 49, p = t % 49;
        float s = part[o][0][p] + part[o][1][p] + part[o][2][p] + part[o][3][p];
        out_cam[((size_t)(i*2 + o)) * MDIM + b*49 + p] = fmaxf(s, 0.f);
    }
}

// ---------------------------------------------------------------------------
// Fused MLP: Linear(1024,512)+ReLU, then sigmoid(l1-l0). Block per (i,b).
// ---------------------------------------------------------------------------
__global__ __launch_bounds__(256) void mlp_fused(
    const float* __restrict__ pooled, const float* __restrict__ p1_w,
    const float* __restrict__ p1_b, const float* __restrict__ p2_w,
    const float* __restrict__ p2_b, float* __restrict__ out)
{
    __shared__ float pl[1024];
    __shared__ float h[512];
    __shared__ float wred[4];
    int i = blockIdx.x >> 5, b = blockIdx.x & 31;
    int t = threadIdx.x;
    const float* pv = pooled + (size_t)(i*BATCH + b) * CFEAT;
    for (int k = t; k < 1024; k += 256) pl[k] = pv[k];
    __syncthreads();
    const float* w1 = p1_w + (size_t)i * 512 * CFEAT;
    for (int j = t; j < 512; j += 256) {
        const float* wr = w1 + (size_t)j * CFEAT;
        float s0 = 0.f, s1 = 0.f, s2 = 0.f, s3 = 0.f;
        for (int k = 0; k < 1024; k += 16) {
            float4 a0 = *(const float4*)(wr + k),      c0 = *(const float4*)(pl + k);
            float4 a1 = *(const float4*)(wr + k + 4),  c1 = *(const float4*)(pl + k + 4);
            float4 a2 = *(const float4*)(wr + k + 8),  c2 = *(const float4*)(pl + k + 8);
            float4 a3 = *(const float4*)(wr + k + 12), c3 = *(const float4*)(pl + k + 12);
            s0 += a0.x*c0.x + a0.y*c0.y + a0.z*c0.z + a0.w*c0.w;
            s1 += a1.x*c1.x + a1.y*c1.y + a1.z*c1.z + a1.w*c1.w;
            s2 += a2.x*c2.x + a2.y*c2.y + a2.z*c2.z + a2.w*c2.w;
            s3 += a3.x*c3.x + a3.y*c3.y + a3.z*c3.z + a3.w*c3.w;
        }
        h[j] = fmaxf(s0 + s1 + s2 + s3 + p1_b[i*512 + j], 0.f);
    }
    __syncthreads();
    const float* w20 = p2_w + (size_t)i * 2 * 512;
    const float* w21 = w20 + 512;
    float d = 0.f;
    for (int k = t; k < 512; k += 256) d += h[k] * (w21[k] - w20[k]);
#pragma unroll
    for (int off = 32; off > 0; off >>= 1) d += __shfl_down(d, off, 64);
    if ((t & 63) == 0) wred[t >> 6] = d;
    __syncthreads();
    if (t == 0) {
        float dd = wred[0] + wred[1] + wred[2] + wred[3]
                 + p2_b[i*2 + 1] - p2_b[i*2 + 0];
        out[b*NSUB + i] = 1.f / (1.f + expf(-dd));
    }
}

// ---------------------------------------------------------------------------
extern "C" void kernel_launch(void* const* d_in, const int* in_sizes, int n_in,
                              void* d_out, int out_size, void* d_ws, size_t ws_size,
                              hipStream_t stream)
{
    const float* x    = (const float*)d_in[0];
    const float* Wb   = (const float*)d_in[1];
    const float* bbp  = (const float*)d_in[2];
    const float* p1w  = (const float*)d_in[3];
    const float* p1b  = (const float*)d_in[4];
    const float* p2w  = (const float*)d_in[5];
    const float* p2b  = (const float*)d_in[6];
    const float* clsw = (const float*)d_in[7];
    float* out = (float*)d_out;

    float* pooled = (float*)d_ws;   // 3*32*1024 f32

    conv_mfma<<<NSUB*13*16, 256, 0, stream>>>(x, Wb, bbp, out);
    pool_kernel<<<(NSUB*BATCH*CFEAT)/256, 256, 0, stream>>>(out + OUT_FEAT, pooled);
    cam_kernel<<<NSUB*BATCH, 256, 0, stream>>>(out + OUT_FEAT, clsw, out + OUT_CAM);
    mlp_fused<<<NSUB*BATCH, 256, 0, stream>>>(pooled, p1w, p1b, p2w, p2b, out);
}

// Round 3
// 140.866 us; speedup vs baseline: 5.7956x; 1.5790x over previous
//
#include <hip/hip_runtime.h>
#include <hip/hip_bf16.h>
#include <math.h>

// Problem constants
#define NSUB   3
#define CFEAT  1024
#define KDIM   3072          // 3 * 32 * 32
#define MDIM   1568          // 32 * 49
#define BATCH  32
#define AROWS  1664          // 13 * 128 (padded M so staging needs no bounds check)

// Output layout (flat f32): ranking[32,3] | cam 3x2x[32,7,7] | feats 3x[32,1024,7,7]
#define OUT_CAM   96
#define OUT_FEAT  9504
#define FEAT_PER_BRANCH (BATCH * CFEAT * 49)   // 1605632

// Workspace byte offsets
#define WS_A      0                                   // bf16 [1664][3072]  10.2 MB
#define WS_W      (AROWS * KDIM * 2)                  // bf16 [3][1024][3072] 18.9 MB
#define WS_POOLED (WS_W + NSUB * CFEAT * KDIM * 2)    // f32  [3][32][1024]
#define WS_H      (WS_POOLED + NSUB * BATCH * CFEAT * 4) // f32 [3][32][512]

typedef __attribute__((ext_vector_type(8))) short bf16x8;
typedef __attribute__((ext_vector_type(4))) float f32x4;

__device__ __forceinline__ short b16(float f){
    __hip_bfloat16 h = __float2bfloat16(f);
    return *reinterpret_cast<short*>(&h);
}
__device__ __forceinline__ bf16x8 pack8(float4 a, float4 b){
    bf16x8 r;
    r[0]=b16(a.x); r[1]=b16(a.y); r[2]=b16(a.z); r[3]=b16(a.w);
    r[4]=b16(b.x); r[5]=b16(b.y); r[6]=b16(b.z); r[7]=b16(b.w);
    return r;
}

// global -> LDS direct copy, 16B per lane (dest = wave-uniform base + lane*16)
typedef const __attribute__((address_space(1))) void* gas1_t;
typedef __attribute__((address_space(3))) void* las3_t;
__device__ __forceinline__ void gl_lds16(const short* g, char* l){
    __builtin_amdgcn_global_load_lds((gas1_t)g, (las3_t)l, 16, 0, 0);
}

// ---------------------------------------------------------------------------
// Prep: Wb (f32) -> bf16, flat copy
// ---------------------------------------------------------------------------
__global__ void prep_w(const float* __restrict__ w, short* __restrict__ o)
{
    int idx = blockIdx.x * blockDim.x + threadIdx.x;   // per 8 elems
    const float4* s = (const float4*)(w + (size_t)idx * 8);
    *(bf16x8*)(o + (size_t)idx * 8) = pack8(s[0], s[1]);
}

// ---------------------------------------------------------------------------
// Prep: im2col x (f32) -> A bf16 [m][k], m=b*49+p, k=ch*1024+r*32+s
// ---------------------------------------------------------------------------
__global__ void prep_a(const float* __restrict__ x, short* __restrict__ o)
{
    int idx = blockIdx.x * blockDim.x + threadIdx.x;   // 0 .. 1568*384-1
    int m  = idx / 384, kq = idx % 384;
    int b  = m / 49, p = m % 49, ph = p / 7, pw = p % 7;
    int k0 = kq * 8;
    int ch = k0 >> 10, r = (k0 >> 5) & 31, s = k0 & 31;
    const float* src = x + (((size_t)(b*3 + ch)*224 + ph*32 + r)*224 + pw*32 + s);
    float4 a = *(const float4*)src, c = *(const float4*)(src + 4);
    *(bf16x8*)(o + (size_t)m * KDIM + k0) = pack8(a, c);
}

// ---------------------------------------------------------------------------
// Conv GEMM, bf16 MFMA, global_load_lds + double-buffered single-barrier pipe.
// BM=128 BN=64 BK=64, 4 waves (2x2), wave tile 64x32.
// LDS buf: A 16KB + B 8KB = 24KB, x2 = 48KB. Swizzle via pre-swizzled SOURCE:
// LDS[row][slot] = G[row][slot ^ (row&7)]; reads use slot ^ (row&7).
// ---------------------------------------------------------------------------
__global__ __launch_bounds__(256, 2) void conv_mfma(
    const short* __restrict__ A, const short* __restrict__ W,
    const float* __restrict__ bb, float* __restrict__ out)
{
    __shared__ __align__(16) char lds[49152];

    int bid = (int)blockIdx.x;
    bid = (bid & 7) * 78 + (bid >> 3);          // bijective XCD swizzle (624=8*78)
    const int i = bid / 208;
    const int rem = bid % 208;
    const int nt = rem / 13, mt = rem % 13;     // mt fastest: B panels L2-resident per XCD

    const int t = threadIdx.x, wv = t >> 6, l = t & 63;

    // ---- staging: per wave, A: 4 instrs (8 rows each), B: 2 instrs ----
    const int lr8 = l >> 3, ls8 = l & 7;
    const short* Ag[4]; int Ad[4];
#pragma unroll
    for (int q = 0; q < 4; ++q) {
        int row = wv*32 + q*8 + lr8;
        int gs  = ls8 ^ (row & 7);              // inverse-swizzled global slot
        Ag[q] = A + (size_t)(mt*128 + row) * KDIM + gs*8;
        Ad[q] = (wv*32 + q*8) * 128;
    }
    const short* Bg[2]; int Bd[2];
#pragma unroll
    for (int q = 0; q < 2; ++q) {
        int row = wv*16 + q*8 + lr8;
        int gs  = ls8 ^ (row & 7);
        Bg[q] = W + ((size_t)i*CFEAT + nt*64 + row) * KDIM + gs*8;
        Bd[q] = 16384 + (wv*16 + q*8) * 128;
    }

    // ---- compute geometry ----
    const int wr = wv >> 1, wc = wv & 1;
    const int lrow = l & 15, lsl = l >> 4;
    int ard[4][2], brd[2][2];
#pragma unroll
    for (int mi = 0; mi < 4; ++mi) {
        int row = wr*64 + mi*16 + lrow;
        ard[mi][0] = row*128 + ((lsl    ) ^ (row & 7))*16;
        ard[mi][1] = row*128 + ((lsl + 4) ^ (row & 7))*16;
    }
#pragma unroll
    for (int ni = 0; ni < 2; ++ni) {
        int row = wc*32 + ni*16 + lrow;
        brd[ni][0] = 16384 + row*128 + ((lsl    ) ^ (row & 7))*16;
        brd[ni][1] = 16384 + row*128 + ((lsl + 4) ^ (row & 7))*16;
    }

    f32x4 acc[4][2] = {};

    // prologue: stage kt=0 into buf0
#pragma unroll
    for (int q = 0; q < 4; ++q) gl_lds16(Ag[q], lds + Ad[q]);
#pragma unroll
    for (int q = 0; q < 2; ++q) gl_lds16(Bg[q], lds + Bd[q]);

    for (int kt = 0; kt < KDIM/64; ++kt) {
        __syncthreads();   // drains stage(kt) (vmcnt) + all reads of the other buf (lgkm)
        if (kt + 1 < KDIM/64) {                 // issue next tile early (overlaps compute)
            const int bo = ((kt+1)&1) * 24576;
            const int ko = (kt+1) * 64;
#pragma unroll
            for (int q = 0; q < 4; ++q) gl_lds16(Ag[q]+ko, lds + bo + Ad[q]);
#pragma unroll
            for (int q = 0; q < 2; ++q) gl_lds16(Bg[q]+ko, lds + bo + Bd[q]);
        }
        const int bo = (kt&1) * 24576;
        bf16x8 af[4][2], bg[2][2];
#pragma unroll
        for (int mi = 0; mi < 4; ++mi) {
            af[mi][0] = *(const bf16x8*)(lds + bo + ard[mi][0]);
            af[mi][1] = *(const bf16x8*)(lds + bo + ard[mi][1]);
        }
#pragma unroll
        for (int ni = 0; ni < 2; ++ni) {
            bg[ni][0] = *(const bf16x8*)(lds + bo + brd[ni][0]);
            bg[ni][1] = *(const bf16x8*)(lds + bo + brd[ni][1]);
        }
#pragma unroll
        for (int kk = 0; kk < 2; ++kk)
#pragma unroll
            for (int mi = 0; mi < 4; ++mi)
#pragma unroll
                for (int ni = 0; ni < 2; ++ni)
                    acc[mi][ni] = __builtin_amdgcn_mfma_f32_16x16x32_bf16(
                        af[mi][kk], bg[ni][kk], acc[mi][ni], 0, 0, 0);
    }

    // epilogue: bias + scatter to feats[i][b][c][p]
    float* featb = out + OUT_FEAT + (size_t)i * FEAT_PER_BRANCH;
    float bias[2];
#pragma unroll
    for (int ni = 0; ni < 2; ++ni)
        bias[ni] = bb[i*CFEAT + nt*64 + wc*32 + ni*16 + lrow];
#pragma unroll
    for (int mi = 0; mi < 4; ++mi) {
        int mbase = mt*128 + wr*64 + mi*16 + lsl*4;
#pragma unroll
        for (int r = 0; r < 4; ++r) {
            int m = mbase + r;
            if (m >= MDIM) continue;
            int b = m/49, p = m%49;
#pragma unroll
            for (int ni = 0; ni < 2; ++ni) {
                int n = nt*64 + wc*32 + ni*16 + lrow;
                featb[(size_t)(b*CFEAT + n)*49 + p] = acc[mi][ni][r] + bias[ni];
            }
        }
    }
}

// ---------------------------------------------------------------------------
// Global average pool
// ---------------------------------------------------------------------------
__global__ void pool_kernel(const float* __restrict__ feat, float* __restrict__ pooled)
{
    int idx = blockIdx.x * blockDim.x + threadIdx.x;   // 0 .. 3*32*1024-1
    const float* f = feat + (size_t)idx * 49;
    float s = 0.f;
#pragma unroll
    for (int p = 0; p < 49; ++p) s += f[p];
    pooled[idx] = s * (1.f / 49.f);
}

// ---------------------------------------------------------------------------
// CAM: block per (i,b); 4 waves split channels; weights staged in LDS.
// ---------------------------------------------------------------------------
__global__ __launch_bounds__(256) void cam_kernel(
    const float* __restrict__ feat, const float* __restrict__ cls_w,
    float* __restrict__ out_cam)
{
    __shared__ float wsh[2048];
    __shared__ float part[2][4][49];
    int i = blockIdx.x >> 5, b = blockIdx.x & 31;
    int t = threadIdx.x;
    const float* w = cls_w + (size_t)i * 2 * CFEAT;
    for (int k = t; k < 2048; k += 256) wsh[k] = w[k];
    __syncthreads();
    int wv = t >> 6, l = t & 63;
    const float* f = feat + ((size_t)(i*BATCH + b)) * CFEAT * 49;
    if (l < 49) {
        float a0 = 0.f, a1 = 0.f;
        for (int c = wv*256; c < wv*256 + 256; ++c) {
            float v = f[(size_t)c*49 + l];
            a0 += wsh[c] * v;
            a1 += wsh[1024 + c] * v;
        }
        part[0][wv][l] = a0;
        part[1][wv][l] = a1;
    }
    __syncthreads();
    if (t < 98) {
        int o = t / 49, p = t % 49;
        float s = part[o][0][p] + part[o][1][p] + part[o][2][p] + part[o][3][p];
        out_cam[((size_t)(i*2 + o)) * MDIM + b*49 + p] = fmaxf(s, 0.f);
    }
}

// ---------------------------------------------------------------------------
// MLP layer 1: weights read once; pooled staged in LDS chunks.
// Grid: 3 branches x 8 j-chunks of 64. Thread: j = jc*64+(t&63), b-group (t>>6)*8.
// ---------------------------------------------------------------------------
__global__ __launch_bounds__(256) void mlp1_kernel(
    const float* __restrict__ pooled, const float* __restrict__ p1w,
    const float* __restrict__ p1b, float* __restrict__ h)
{
    __shared__ float ps[32 * 256];
    int i = blockIdx.x >> 3, jc = blockIdx.x & 7;
    int t = threadIdx.x;
    int j = jc*64 + (t & 63);
    int bg = (t >> 6) * 8;
    float acc[8] = {};
    const float* wrow = p1w + ((size_t)i*512 + j) * CFEAT;
    for (int kc = 0; kc < 4; ++kc) {
        __syncthreads();
#pragma unroll
        for (int q = 0; q < 8; ++q) {
            int f4 = t + q*256;                  // 0..2047 float4s
            int b = f4 >> 6, k4 = (f4 & 63) * 4;
            *(float4*)&ps[b*256 + k4] =
                *(const float4*)&pooled[((size_t)i*32 + b)*CFEAT + kc*256 + k4];
        }
        __syncthreads();
        const float* wk = wrow + kc*256;
        for (int k = 0; k < 256; k += 4) {
            float4 w4 = *(const float4*)(wk + k);
#pragma unroll
            for (int q = 0; q < 8; ++q) {
                const float* pr = &ps[(bg + q)*256 + k];   // same addr across wave: broadcast
                acc[q] += w4.x*pr[0] + w4.y*pr[1] + w4.z*pr[2] + w4.w*pr[3];
            }
        }
    }
    float bias = p1b[i*512 + j];
#pragma unroll
    for (int q = 0; q < 8; ++q)
        h[((size_t)i*32 + bg + q)*512 + j] = fmaxf(acc[q] + bias, 0.f);
}

// ---------------------------------------------------------------------------
// MLP layer 2 + softmax[:,1]: block per branch.
// ---------------------------------------------------------------------------
__global__ void mlp2_kernel(const float* __restrict__ h, const float* __restrict__ p2w,
                            const float* __restrict__ p2b, float* __restrict__ out)
{
    __shared__ float part[256];
    int i = blockIdx.x, t = threadIdx.x;
    int b = t & 31, kc = t >> 5;                 // kc 0..7, 64 k each
    const float* hv = h + ((size_t)i*32 + b)*512 + kc*64;
    const float* w0 = p2w + (size_t)i*1024 + kc*64;
    const float* w1 = w0 + 512;
    float s = 0.f;
    for (int k = 0; k < 64; ++k) s += hv[k] * (w1[k] - w0[k]);
    part[t] = s;
    __syncthreads();
    if (t < 32) {
        float d = 0.f;
#pragma unroll
        for (int q = 0; q < 8; ++q) d += part[q*32 + t];
        d += p2b[i*2 + 1] - p2b[i*2 + 0];
        out[b*NSUB + i] = 1.f / (1.f + expf(-d));
    }
}

// ---------------------------------------------------------------------------
extern "C" void kernel_launch(void* const* d_in, const int* in_sizes, int n_in,
                              void* d_out, int out_size, void* d_ws, size_t ws_size,
                              hipStream_t stream)
{
    const float* x    = (const float*)d_in[0];
    const float* Wb   = (const float*)d_in[1];
    const float* bbp  = (const float*)d_in[2];
    const float* p1w  = (const float*)d_in[3];
    const float* p1b  = (const float*)d_in[4];
    const float* p2w  = (const float*)d_in[5];
    const float* p2b  = (const float*)d_in[6];
    const float* clsw = (const float*)d_in[7];
    float* out = (float*)d_out;

    char* ws = (char*)d_ws;
    short* A_bf   = (short*)(ws + WS_A);
    short* W_bf   = (short*)(ws + WS_W);
    float* pooled = (float*)(ws + WS_POOLED);
    float* hbuf   = (float*)(ws + WS_H);

    prep_w<<<(NSUB*CFEAT*KDIM/8)/256, 256, 0, stream>>>(Wb, W_bf);     // 4608 blocks
    prep_a<<<(MDIM*(KDIM/8))/256, 256, 0, stream>>>(x, A_bf);          // 2352 blocks
    conv_mfma<<<NSUB*13*16, 256, 0, stream>>>(A_bf, W_bf, bbp, out);
    pool_kernel<<<(NSUB*BATCH*CFEAT)/256, 256, 0, stream>>>(out + OUT_FEAT, pooled);
    cam_kernel<<<NSUB*BATCH, 256, 0, stream>>>(out + OUT_FEAT, clsw, out + OUT_CAM);
    mlp1_kernel<<<NSUB*8, 256, 0, stream>>>(pooled, p1w, p1b, hbuf);
    mlp2_kernel<<<NSUB, 256, 0, stream>>>(hbuf, p2w, p2b, out);
}